// Round 13
// baseline (698.303 us; speedup 1.0000x reference)
//
#include <hip/hip_runtime.h>
#include <hip/hip_bf16.h>

typedef __attribute__((ext_vector_type(8))) short short8;
typedef __attribute__((ext_vector_type(4))) short short4v;
typedef __attribute__((ext_vector_type(4))) float float4v;

__device__ __forceinline__ short f2bf(float f) {
  union { float f; unsigned u; } v; v.f = f;
  unsigned r = v.u + 0x7fffu + ((v.u >> 16) & 1u);  // RNE
  return (short)(r >> 16);
}

typedef const __attribute__((address_space(1))) unsigned int* as1_u32p;
typedef __attribute__((address_space(3))) unsigned int* as3_u32p;

__device__ __forceinline__ void gl_lds16(const void* g, void* l) {
  // async global->LDS, 16B/lane, dest = wave-uniform base + lane*16
  __builtin_amdgcn_global_load_lds((as1_u32p)g, (as3_u32p)l, 16, 0, 0);
}

// ---------------------------------------------------------------------------
// Kernel P: fused prep = dequant int4->bf16 W^T [N,K] + A fp32->bf16.
// (round-5 version — part of the best-measured configuration)
// ---------------------------------------------------------------------------
__global__ __launch_bounds__(256, 4)
void prep_kernel(const int* __restrict__ qw,      // [K, N/8]
                 const float* __restrict__ scales,// [K/G, N]
                 const int* __restrict__ qzeros,  // [K/G, N/8]
                 short* __restrict__ Bt,          // [N, K] bf16 out
                 const float* __restrict__ inp,   // [M, K] fp32
                 short* __restrict__ Abf,         // [M, K] bf16 out
                 int K, int N, int G, int nDq, long long nA)
{
  constexpr int KP = 72;                 // padded k-stride (shorts)
  __shared__ short Ls[256 * KP];         // ~36 KB

  if ((int)blockIdx.x >= nDq) {
    // ---- aconv part ----
    const long long i =
        (((long long)blockIdx.x - nDq) * blockDim.x + threadIdx.x) * 8;
    if (i >= nA) return;
    const float4v a = *(const float4v*)(inp + i);
    const float4v b = *(const float4v*)(inp + i + 4);
    short8 h;
    h[0] = f2bf(a[0]); h[1] = f2bf(a[1]); h[2] = f2bf(a[2]); h[3] = f2bf(a[3]);
    h[4] = f2bf(b[0]); h[5] = f2bf(b[1]); h[6] = f2bf(b[2]); h[7] = f2bf(b[3]);
    *(short8*)(Abf + i) = h;
    return;
  }

  // ---- dequant part ----
  const int KB  = K >> 6;
  const int N8  = N >> 3;
  const int k0  = ((int)blockIdx.x % KB) * 64;
  const int nb  = (int)blockIdx.x / KB;
  const int n0  = nb * 256;
  const int n80 = nb * 32;
  const int g   = k0 / G;
  const int t   = threadIdx.x;
  const int kloc = t >> 3;               // 0..31
  const int w4   = (t & 7) * 4;          // int4-word offset 0..28

  const int4 z4 = *(const int4*)(qzeros + (size_t)g * N8 + n80 + w4);
  const int za[4] = {z4.x, z4.y, z4.z, z4.w};
  float sc[32];
  #pragma unroll
  for (int ii = 0; ii < 8; ++ii)
    *(float4v*)(sc + ii * 4) =
        *(const float4v*)(scales + (size_t)g * N + n0 + w4 * 8 + ii * 4);

  #pragma unroll
  for (int kh = 0; kh < 2; ++kh) {
    const int k = kloc + kh * 32;
    const int4 q4 = *(const int4*)(qw + (size_t)(k0 + k) * N8 + n80 + w4);
    const int qa[4] = {q4.x, q4.y, q4.z, q4.w};
    #pragma unroll
    for (int ii = 0; ii < 4; ++ii) {
      #pragma unroll
      for (int j = 0; j < 8; ++j) {
        const float z = (float)((za[ii] >> (4 * j)) & 0xF);
        const float q = (float)((qa[ii] >> (4 * j)) & 0xF);
        Ls[(w4 * 8 + ii * 8 + j) * KP + k] = f2bf((q - z) * sc[ii * 8 + j]);
      }
    }
  }
  __syncthreads();

  #pragma unroll
  for (int it = 0; it < 8; ++it) {
    const int idx = t + it * 256;        // 0..2047
    const int row = idx >> 3;            // 0..255
    const int ch  = (idx & 7) * 8;       // k element offset
    const short8 v = *(const short8*)(&Ls[row * KP + ch]);
    *(short8*)(Bt + (size_t)(n0 + row) * K + k0 + ch) = v;
  }
}

// ---------------------------------------------------------------------------
// Fallback prep kernels (odd shapes)
// ---------------------------------------------------------------------------
__global__ __launch_bounds__(256, 2)
void dequant_kernel_v0(const int* __restrict__ qw,
                       const float* __restrict__ scales,
                       const int* __restrict__ qzeros,
                       short* __restrict__ Bt,
                       int K, int N, int G)
{
  __shared__ short Ls[128 * 64];   // [n_local][k_local]
  const int N8  = N >> 3;
  const int k0  = blockIdx.x * 64;
  const int n80 = blockIdx.y * 16;
  const int g   = k0 / G;
  const int tid  = threadIdx.x;
  const int lane = tid & 63;
  const int w    = tid >> 6;

  const int4 q4 = *(const int4*)(qw + (size_t)(k0 + lane) * N8 + n80 + w * 4);
  const int4 z4 = *(const int4*)(qzeros + (size_t)g * N8 + n80 + w * 4);
  const int qa[4] = {q4.x, q4.y, q4.z, q4.w};
  const int za[4] = {z4.x, z4.y, z4.z, z4.w};

  #pragma unroll
  for (int it = 0; it < 4; ++it) {
    const int n8l = w * 4 + it;
    const float4v s0 = *(const float4v*)(scales + (size_t)g * N + (n80 + n8l) * 8);
    const float4v s1 = *(const float4v*)(scales + (size_t)g * N + (n80 + n8l) * 8 + 4);
    const float sc[8] = {s0[0], s0[1], s0[2], s0[3], s1[0], s1[1], s1[2], s1[3]};
    const int wq = qa[it], wz = za[it];
    #pragma unroll
    for (int j = 0; j < 8; ++j) {
      const float z = (float)((wz >> (4 * j)) & 0xF);
      const float q = (float)((wq >> (4 * j)) & 0xF);
      Ls[(n8l * 8 + j) * 64 + lane] = f2bf((q - z) * sc[j]);
    }
  }
  __syncthreads();

  #pragma unroll
  for (int it = 0; it < 4; ++it) {
    const int c   = tid + it * 256;
    const int row = c >> 3;
    const int off = (c & 7) * 8;
    const short8 v = *(const short8*)(&Ls[row * 64 + off]);
    *(short8*)(Bt + (size_t)(n80 * 8 + row) * K + k0 + off) = v;
  }
}

__global__ __launch_bounds__(256, 4)
void aconv_kernel(const float* __restrict__ in, short* __restrict__ out, long long n)
{
  const long long i = ((long long)blockIdx.x * blockDim.x + threadIdx.x) * 8;
  if (i >= n) return;
  const float4v a = *(const float4v*)(in + i);
  const float4v b = *(const float4v*)(in + i + 4);
  short8 h;
  h[0] = f2bf(a[0]); h[1] = f2bf(a[1]); h[2] = f2bf(a[2]); h[3] = f2bf(a[3]);
  h[4] = f2bf(b[0]); h[5] = f2bf(b[1]); h[6] = f2bf(b[2]); h[7] = f2bf(b[3]);
  *(short8*)(out + i) = h;
}

// ---------------------------------------------------------------------------
// Kernel 3: 256x256 bf16 GEMM + bias + silu + mul. 8 waves (2M x 4N), BK=64,
// 128 KiB LDS double-buffer, swizzled (pre-swizzled global src + swizzled read).
// ROUND-13: ONE variable changed vs the 439-us config: BARRIERS 8 -> 1/tile.
// Every r1-r9 schedule variant shared 8-9 barriers/tile; m233 measured
// stage+vmcnt+barrier as ~72% of a 2-phase loop's gap. New body:
//   { stage all 8 gl_lds (t+1 -> nxt); read all 24 frags from cur;
//     64 MFMA, fully compiler-scheduled; __syncthreads(); }
// Correctness (m97 argument): stage targets nxt only, whose last reads
// completed before the PREVIOUS __syncthreads (lgkmcnt(0) in it); RAW on
// cur is covered by the same barrier's vmcnt(0), with full-tile issue->wait
// cover (~3000 cyc >> 900 cyc HBM). No setprio / sched_barrier / manual
// waits — those all measured null on this structure.
// ---------------------------------------------------------------------------
__global__ __launch_bounds__(512, 2)
void gemm256_silu_mul_kernel(const short* __restrict__ A,   // [M,K] bf16
                             const short* __restrict__ Bt,  // [N,K] bf16
                             const float* __restrict__ bias,
                             const float* __restrict__ mulp,
                             float*       __restrict__ out,
                             int M, int N, int K)
{
  __shared__ short L[2][2][16384];   // [buf][A|B][32 subtiles * 512] = 128 KiB

  const int tid  = threadIdx.x;
  const int lane = tid & 63;
  const int wave = tid >> 6;   // 0..7
  const int wm   = wave >> 2;  // 0..1 : row half
  const int wn   = wave & 3;   // 0..3 : col quarter

  // bijective XCD-aware swizzle of the linear block id (m204 variant)
  const int nwg = gridDim.x;
  const int q8 = nwg >> 3, r8 = nwg & 7;
  const int xcd = blockIdx.x & 7, sub = blockIdx.x >> 3;
  const int swz = (xcd < r8 ? xcd * (q8 + 1) : r8 * (q8 + 1) + (xcd - r8) * q8) + sub;
  const int nbx = N >> 8;
  const int bx = swz % nbx, by = swz / nbx;
  const int m0 = by << 8, n0 = bx << 8;

  const short* Ab = A  + (size_t)m0 * K;
  const short* Bb = Bt + (size_t)n0 * K;

  // staging source geometry (pre-swizzled global column; linear LDS dest)
  const int srow = lane >> 2;                               // 0..15 subtile row
  const int scol = (((lane & 3) ^ ((lane & 32) >> 4))) * 8; // pre-swizzled k slot
  // fragment-read geometry (swizzled ds_read address)
  const int fm = lane & 15;
  const int ko = ((lane >> 4) * 8) ^ ((fm & 8) ? 16 : 0);   // k elem offset

  // staging group ownership (16-row groups, 2 subtiles each)
  const int BG0 = wave * 2;
  const int BG1 = wave * 2 + 1;
  const int AEg = (wave & 3) + (wave >> 2) * 8;  // A groups {0-3,8-11}
  const int ALg = AEg + 4;                       // A groups {4-7,12-15}

  float4v acc[8][4];
  #pragma unroll
  for (int i = 0; i < 8; ++i)
    #pragma unroll
    for (int j = 0; j < 4; ++j)
      acc[i][j] = (float4v){0.f, 0.f, 0.f, 0.f};

  const int NT = K >> 6;

  auto stage2 = [&](int buf, int ab, int g, const short* __restrict__ base, int kk) {
    #pragma unroll
    for (int ks = 0; ks < 2; ++ks)
      gl_lds16(base + (size_t)(g * 16 + srow) * K + kk + ks * 32 + scol,
               &L[buf][ab][(g * 2 + ks) * 512]);
  };

  // prologue: tile 0 -> buf 0
  stage2(0, 1, BG0, Bb, 0);
  stage2(0, 1, BG1, Bb, 0);
  stage2(0, 0, AEg, Ab, 0);
  stage2(0, 0, ALg, Ab, 0);
  __syncthreads();

  for (int t = 0; t < NT; ++t) {
    const int cur = t & 1;
    const int nxt = cur ^ 1;

    // stage t+1 into the other buffer (in flight across the whole tile body)
    if (t + 1 < NT) {
      const int kk1 = (t + 1) << 6;
      stage2(nxt, 1, BG0, Bb, kk1);
      stage2(nxt, 1, BG1, Bb, kk1);
      stage2(nxt, 0, AEg, Ab, kk1);
      stage2(nxt, 0, ALg, Ab, kk1);
    }

    // compute: all 24 fragment reads + 64 MFMAs, compiler-scheduled
    short8 af[4][2], bf[4][2];
    #pragma unroll
    for (int j = 0; j < 4; ++j)
      #pragma unroll
      for (int ks = 0; ks < 2; ++ks)
        bf[j][ks] = *(const short8*)(
            &L[cur][1][((wn * 4 + j) * 2 + ks) * 512 + fm * 32 + ko]);

    #pragma unroll
    for (int i = 0; i < 4; ++i)
      #pragma unroll
      for (int ks = 0; ks < 2; ++ks)
        af[i][ks] = *(const short8*)(
            &L[cur][0][((wm * 8 + i) * 2 + ks) * 512 + fm * 32 + ko]);
    #pragma unroll
    for (int i = 0; i < 4; ++i)
      #pragma unroll
      for (int j = 0; j < 4; ++j)
        #pragma unroll
        for (int ks = 0; ks < 2; ++ks)
          acc[i][j] = __builtin_amdgcn_mfma_f32_16x16x32_bf16(
              af[i][ks], bf[j][ks], acc[i][j], 0, 0, 0);

    #pragma unroll
    for (int i = 0; i < 4; ++i)
      #pragma unroll
      for (int ks = 0; ks < 2; ++ks)
        af[i][ks] = *(const short8*)(
            &L[cur][0][((wm * 8 + 4 + i) * 2 + ks) * 512 + fm * 32 + ko]);
    #pragma unroll
    for (int i = 0; i < 4; ++i)
      #pragma unroll
      for (int j = 0; j < 4; ++j)
        #pragma unroll
        for (int ks = 0; ks < 2; ++ks)
          acc[4 + i][j] = __builtin_amdgcn_mfma_f32_16x16x32_bf16(
              af[i][ks], bf[j][ks], acc[4 + i][j], 0, 0, 0);

    // single barrier per tile: drains gl_lds (vmcnt) + ds reads (lgkm),
    // fences LDS motion, and releases nxt for the next iteration's stage.
    __syncthreads();
  }

  // epilogue: bias + silu + mul
  const int cn  = lane & 15;
  const int cr4 = (lane >> 4) * 4;
  #pragma unroll
  for (int mt = 0; mt < 8; ++mt) {
    #pragma unroll
    for (int nt = 0; nt < 4; ++nt) {
      const int n  = n0 + wn * 64 + nt * 16 + cn;
      const float bn = bias[n];
      #pragma unroll
      for (int i = 0; i < 4; ++i) {
        const int m = m0 + wm * 128 + mt * 16 + cr4 + i;
        float x = acc[mt][nt][i] + bn;
        float s = x / (1.0f + __expf(-x));
        out[(size_t)m * N + n] = s * mulp[(size_t)m * N + n];
      }
    }
  }
}

// ---------------------------------------------------------------------------
// Kernel 3 (fallback shapes): 128x128 m97-structure GEMM
// ---------------------------------------------------------------------------
__global__ __launch_bounds__(256, 2)
void gemm_silu_mul_kernel(const short* __restrict__ A,
                          const short* __restrict__ Bt,
                          const float* __restrict__ bias,
                          const float* __restrict__ mulp,
                          float*       __restrict__ out,
                          int M, int N, int K)
{
  __shared__ short As[128 * 64];
  __shared__ short Bs[128 * 64];

  const int tid  = threadIdx.x;
  const int lane = tid & 63;
  const int wave = tid >> 6;
  const int wr = (wave >> 1) * 64;
  const int wc = (wave & 1) * 64;
  const int m0 = blockIdx.y * 128;
  const int n0 = blockIdx.x * 128;

  float4v acc[4][4];
  #pragma unroll
  for (int i = 0; i < 4; ++i)
    #pragma unroll
    for (int j = 0; j < 4; ++j)
      acc[i][j] = (float4v){0.f, 0.f, 0.f, 0.f};

  const int fm = lane & 15;
  const int fk = (lane >> 4) * 8;
  const int srow = lane >> 3;
  const int scol = (lane & 7) * 8;

  for (int k0 = 0; k0 < K; k0 += 64) {
    #pragma unroll
    for (int c = 0; c < 4; ++c) {
      const int chunk = wave * 4 + c;
      const int row   = chunk * 8 + srow;
      gl_lds16(A  + (size_t)(m0 + row) * K + k0 + scol, &As[chunk * 512]);
      gl_lds16(Bt + (size_t)(n0 + row) * K + k0 + scol, &Bs[chunk * 512]);
    }
    __syncthreads();

    #pragma unroll
    for (int ks = 0; ks < 64; ks += 32) {
      short8 a[4], b[4];
      #pragma unroll
      for (int mt = 0; mt < 4; ++mt)
        a[mt] = *(const short8*)(&As[(wr + mt * 16 + fm) * 64 + ks + fk]);
      #pragma unroll
      for (int nt = 0; nt < 4; ++nt)
        b[nt] = *(const short8*)(&Bs[(wc + nt * 16 + fm) * 64 + ks + fk]);
      #pragma unroll
      for (int mt = 0; mt < 4; ++mt)
        #pragma unroll
        for (int nt = 0; nt < 4; ++nt)
          acc[mt][nt] = __builtin_amdgcn_mfma_f32_16x16x32_bf16(a[mt], b[nt], acc[mt][nt], 0, 0, 0);
    }
    __syncthreads();
  }

  const int cn = lane & 15;
  const int cr = (lane >> 4) * 4;
  #pragma unroll
  for (int mt = 0; mt < 4; ++mt) {
    #pragma unroll
    for (int nt = 0; nt < 4; ++nt) {
      const int n  = n0 + wc + nt * 16 + cn;
      const float bn = bias[n];
      #pragma unroll
      for (int i = 0; i < 4; ++i) {
        const int m = m0 + wr + mt * 16 + cr + i;
        float x = acc[mt][nt][i] + bn;
        float s = x / (1.0f + __expf(-x));
        out[(size_t)m * N + n] = s * mulp[(size_t)m * N + n];
      }
    }
  }
}

// ---------------------------------------------------------------------------
// Fallback: round-1 fused kernel (used only if ws_size is too small)
// ---------------------------------------------------------------------------
#define BM 128
#define BN 128
#define BK 64
#define LDA 72
#define LDB 72

__global__ __launch_bounds__(256, 2)
void woq_silu_mul_kernel(const float* __restrict__ inp, const int* __restrict__ qw,
                         const float* __restrict__ scales, const int* __restrict__ qzeros,
                         const float* __restrict__ bias, const float* __restrict__ mulp,
                         float* __restrict__ out, int M, int N, int K, int G)
{
  __shared__ short As[BM * LDA];
  __shared__ short Bs[BN * LDB];
  const int tid  = threadIdx.x;
  const int lane = tid & 63;
  const int wave = tid >> 6;
  const int wr = (wave >> 1) * 64;
  const int wc = (wave & 1) * 64;
  const int m0 = blockIdx.y * BM;
  const int n0 = blockIdx.x * BN;
  const int N8 = N >> 3;
  float4v acc[4][4];
  #pragma unroll
  for (int i = 0; i < 4; ++i)
    #pragma unroll
    for (int j = 0; j < 4; ++j)
      acc[i][j] = (float4v){0.f, 0.f, 0.f, 0.f};
  const int n8l  = tid >> 4;
  const int kloc = (tid & 15) * 4;
  const int fm = lane & 15;
  const int fk = (lane >> 4) * 8;
  for (int k0 = 0; k0 < K; k0 += BK) {
    #pragma unroll
    for (int i = 0; i < 8; ++i) {
      int f = tid + i * 256;
      int row = f >> 4;
      int col = (f & 15) * 4;
      float4v a4 = *(const float4v*)(inp + (size_t)(m0 + row) * K + k0 + col);
      short4v h;
      h[0] = f2bf(a4[0]); h[1] = f2bf(a4[1]); h[2] = f2bf(a4[2]); h[3] = f2bf(a4[3]);
      *(short4v*)(&As[row * LDA + col]) = h;
    }
    {
      const int g = k0 / G;
      const int n8g = (n0 >> 3) + n8l;
      const int zw = qzeros[(size_t)g * N8 + n8g];
      const float4v s0 = *(const float4v*)(scales + (size_t)g * N + n0 + n8l * 8);
      const float4v s1 = *(const float4v*)(scales + (size_t)g * N + n0 + n8l * 8 + 4);
      float sc[8] = {s0[0], s0[1], s0[2], s0[3], s1[0], s1[1], s1[2], s1[3]};
      int w[4];
      #pragma unroll
      for (int kk = 0; kk < 4; ++kk)
        w[kk] = qw[(size_t)(k0 + kloc + kk) * N8 + n8g];
      #pragma unroll
      for (int j = 0; j < 8; ++j) {
        const float zj = (float)((zw >> (4 * j)) & 0xF);
        const float sj = sc[j];
        short4v h;
        #pragma unroll
        for (int kk = 0; kk < 4; ++kk) {
          int q = (w[kk] >> (4 * j)) & 0xF;
          h[kk] = f2bf(((float)q - zj) * sj);
        }
        *(short4v*)(&Bs[(n8l * 8 + j) * LDB + kloc]) = h;
      }
    }
    __syncthreads();
    #pragma unroll
    for (int ks = 0; ks < BK; ks += 32) {
      short8 a[4], b[4];
      #pragma unroll
      for (int mt = 0; mt < 4; ++mt)
        a[mt] = *(const short8*)(&As[(wr + mt * 16 + fm) * LDA + ks + fk]);
      #pragma unroll
      for (int nt = 0; nt < 4; ++nt)
        b[nt] = *(const short8*)(&Bs[(wc + nt * 16 + fm) * LDB + ks + fk]);
      #pragma unroll
      for (int mt = 0; mt < 4; ++mt)
        #pragma unroll
        for (int nt = 0; nt < 4; ++nt)
          acc[mt][nt] = __builtin_amdgcn_mfma_f32_16x16x32_bf16(a[mt], b[nt], acc[mt][nt], 0, 0, 0);
    }
    __syncthreads();
  }
  const int cn = lane & 15;
  const int cr = (lane >> 4) * 4;
  #pragma unroll
  for (int mt = 0; mt < 4; ++mt) {
    #pragma unroll
    for (int nt = 0; nt < 4; ++nt) {
      const int n = n0 + wc + nt * 16 + cn;
      const float bn = bias[n];
      #pragma unroll
      for (int i = 0; i < 4; ++i) {
        const int m = m0 + wr + mt * 16 + cr + i;
        float x = acc[mt][nt][i] + bn;
        float s = x / (1.0f + __expf(-x));
        out[(size_t)m * N + n] = s * mulp[(size_t)m * N + n];
      }
    }
  }
}

extern "C" void kernel_launch(void* const* d_in, const int* in_sizes, int n_in,
                              void* d_out, int out_size, void* d_ws, size_t ws_size,
                              hipStream_t stream) {
  const float* inp    = (const float*)d_in[0];
  const int*   qw     = (const int*)d_in[1];
  const float* scales = (const float*)d_in[2];
  const int*   qzeros = (const int*)d_in[3];
  const float* bias   = (const float*)d_in[4];
  const float* mulp   = (const float*)d_in[5];
  float*       out    = (float*)d_out;

  const int N = in_sizes[4];
  const int K = (int)(((long long)in_sizes[1] * 8) / N);
  const int M = (int)((long long)in_sizes[0] / K);
  const int G = K / (in_sizes[2] / N);

  const size_t btBytes = (size_t)N * K * sizeof(short);
  const size_t aBytes  = (size_t)M * K * sizeof(short);

  if (ws_size >= btBytes + aBytes) {
    short* Bt  = (short*)d_ws;
    short* Abf = (short*)((char*)d_ws + btBytes);
    const long long nA = (long long)M * K;

    const bool dqOk = (N & 255) == 0 && (K & 63) == 0 && G >= 64 && (G & 63) == 0
                      && (nA & 7) == 0;
    if (dqOk) {
      const int nDq = (K / 64) * (N / 256);
      const int nAc = (int)((nA / 8 + 255) / 256);
      prep_kernel<<<dim3((unsigned)(nDq + nAc)), dim3(256), 0, stream>>>(
          qw, scales, qzeros, Bt, inp, Abf, K, N, G, nDq, nA);
    } else {
      dim3 dq_grid(K / 64, (N / 8) / 16);
      dequant_kernel_v0<<<dq_grid, dim3(256), 0, stream>>>(qw, scales, qzeros, Bt, K, N, G);
      aconv_kernel<<<dim3((unsigned)((nA / 8 + 255) / 256)), dim3(256), 0, stream>>>(inp, Abf, nA);
    }

    if ((M & 255) == 0 && (N & 255) == 0 && (K & 63) == 0) {
      dim3 grid((unsigned)((N >> 8) * (M >> 8)));
      gemm256_silu_mul_kernel<<<grid, dim3(512), 0, stream>>>(Abf, Bt, bias, mulp, out, M, N, K);
    } else {
      dim3 grid(N / 128, M / 128);
      gemm_silu_mul_kernel<<<grid, dim3(256), 0, stream>>>(Abf, Bt, bias, mulp, out, M, N, K);
    }
  } else {
    dim3 grid(N / BN, M / BM);
    woq_silu_mul_kernel<<<grid, dim3(256), 0, stream>>>(inp, qw, scales, qzeros,
                                                        bias, mulp, out, M, N, K, G);
  }
}

// Round 14
// 697.063 us; speedup vs baseline: 1.0018x; 1.0018x over previous
//
#include <hip/hip_runtime.h>
#include <hip/hip_bf16.h>

typedef __attribute__((ext_vector_type(8))) short short8;
typedef __attribute__((ext_vector_type(4))) short short4v;
typedef __attribute__((ext_vector_type(4))) float float4v;

__device__ __forceinline__ short f2bf(float f) {
  union { float f; unsigned u; } v; v.f = f;
  unsigned r = v.u + 0x7fffu + ((v.u >> 16) & 1u);  // RNE
  return (short)(r >> 16);
}

typedef const __attribute__((address_space(1))) unsigned int* as1_u32p;
typedef __attribute__((address_space(3))) unsigned int* as3_u32p;

__device__ __forceinline__ void gl_lds16(const void* g, void* l) {
  // async global->LDS, 16B/lane, dest = wave-uniform base + lane*16
  __builtin_amdgcn_global_load_lds((as1_u32p)g, (as3_u32p)l, 16, 0, 0);
}

// ---------------------------------------------------------------------------
// Kernel P: fused prep = dequant int4->bf16 W^T [N,K] + A fp32->bf16.
// ---------------------------------------------------------------------------
__global__ __launch_bounds__(256, 4)
void prep_kernel(const int* __restrict__ qw,      // [K, N/8]
                 const float* __restrict__ scales,// [K/G, N]
                 const int* __restrict__ qzeros,  // [K/G, N/8]
                 short* __restrict__ Bt,          // [N, K] bf16 out
                 const float* __restrict__ inp,   // [M, K] fp32
                 short* __restrict__ Abf,         // [M, K] bf16 out
                 int K, int N, int G, int nDq, long long nA)
{
  constexpr int KP = 72;                 // padded k-stride (shorts)
  __shared__ short Ls[256 * KP];         // ~36 KB

  if ((int)blockIdx.x >= nDq) {
    // ---- aconv part ----
    const long long i =
        (((long long)blockIdx.x - nDq) * blockDim.x + threadIdx.x) * 8;
    if (i >= nA) return;
    const float4v a = *(const float4v*)(inp + i);
    const float4v b = *(const float4v*)(inp + i + 4);
    short8 h;
    h[0] = f2bf(a[0]); h[1] = f2bf(a[1]); h[2] = f2bf(a[2]); h[3] = f2bf(a[3]);
    h[4] = f2bf(b[0]); h[5] = f2bf(b[1]); h[6] = f2bf(b[2]); h[7] = f2bf(b[3]);
    *(short8*)(Abf + i) = h;
    return;
  }

  // ---- dequant part ----
  const int KB  = K >> 6;
  const int N8  = N >> 3;
  const int k0  = ((int)blockIdx.x % KB) * 64;
  const int nb  = (int)blockIdx.x / KB;
  const int n0  = nb * 256;
  const int n80 = nb * 32;
  const int g   = k0 / G;
  const int t   = threadIdx.x;
  const int kloc = t >> 3;               // 0..31
  const int w4   = (t & 7) * 4;          // int4-word offset 0..28

  const int4 z4 = *(const int4*)(qzeros + (size_t)g * N8 + n80 + w4);
  const int za[4] = {z4.x, z4.y, z4.z, z4.w};
  float sc[32];
  #pragma unroll
  for (int ii = 0; ii < 8; ++ii)
    *(float4v*)(sc + ii * 4) =
        *(const float4v*)(scales + (size_t)g * N + n0 + w4 * 8 + ii * 4);

  #pragma unroll
  for (int kh = 0; kh < 2; ++kh) {
    const int k = kloc + kh * 32;
    const int4 q4 = *(const int4*)(qw + (size_t)(k0 + k) * N8 + n80 + w4);
    const int qa[4] = {q4.x, q4.y, q4.z, q4.w};
    #pragma unroll
    for (int ii = 0; ii < 4; ++ii) {
      #pragma unroll
      for (int j = 0; j < 8; ++j) {
        const float z = (float)((za[ii] >> (4 * j)) & 0xF);
        const float q = (float)((qa[ii] >> (4 * j)) & 0xF);
        Ls[(w4 * 8 + ii * 8 + j) * KP + k] = f2bf((q - z) * sc[ii * 8 + j]);
      }
    }
  }
  __syncthreads();

  #pragma unroll
  for (int it = 0; it < 8; ++it) {
    const int idx = t + it * 256;        // 0..2047
    const int row = idx >> 3;            // 0..255
    const int ch  = (idx & 7) * 8;       // k element offset
    const short8 v = *(const short8*)(&Ls[row * KP + ch]);
    *(short8*)(Bt + (size_t)(n0 + row) * K + k0 + ch) = v;
  }
}

// ---------------------------------------------------------------------------
// Fallback prep kernels (odd shapes)
// ---------------------------------------------------------------------------
__global__ __launch_bounds__(256, 2)
void dequant_kernel_v0(const int* __restrict__ qw,
                       const float* __restrict__ scales,
                       const int* __restrict__ qzeros,
                       short* __restrict__ Bt,
                       int K, int N, int G)
{
  __shared__ short Ls[128 * 64];   // [n_local][k_local]
  const int N8  = N >> 3;
  const int k0  = blockIdx.x * 64;
  const int n80 = blockIdx.y * 16;
  const int g   = k0 / G;
  const int tid  = threadIdx.x;
  const int lane = tid & 63;
  const int w    = tid >> 6;

  const int4 q4 = *(const int4*)(qw + (size_t)(k0 + lane) * N8 + n80 + w * 4);
  const int4 z4 = *(const int4*)(qzeros + (size_t)g * N8 + n80 + w * 4);
  const int qa[4] = {q4.x, q4.y, q4.z, q4.w};
  const int za[4] = {z4.x, z4.y, z4.z, z4.w};

  #pragma unroll
  for (int it = 0; it < 4; ++it) {
    const int n8l = w * 4 + it;
    const float4v s0 = *(const float4v*)(scales + (size_t)g * N + (n80 + n8l) * 8);
    const float4v s1 = *(const float4v*)(scales + (size_t)g * N + (n80 + n8l) * 8 + 4);
    const float sc[8] = {s0[0], s0[1], s0[2], s0[3], s1[0], s1[1], s1[2], s1[3]};
    const int wq = qa[it], wz = za[it];
    #pragma unroll
    for (int j = 0; j < 8; ++j) {
      const float z = (float)((wz >> (4 * j)) & 0xF);
      const float q = (float)((wq >> (4 * j)) & 0xF);
      Ls[(n8l * 8 + j) * 64 + lane] = f2bf((q - z) * sc[j]);
    }
  }
  __syncthreads();

  #pragma unroll
  for (int it = 0; it < 4; ++it) {
    const int c   = tid + it * 256;
    const int row = c >> 3;
    const int off = (c & 7) * 8;
    const short8 v = *(const short8*)(&Ls[row * 64 + off]);
    *(short8*)(Bt + (size_t)(n80 * 8 + row) * K + k0 + off) = v;
  }
}

__global__ __launch_bounds__(256, 4)
void aconv_kernel(const float* __restrict__ in, short* __restrict__ out, long long n)
{
  const long long i = ((long long)blockIdx.x * blockDim.x + threadIdx.x) * 8;
  if (i >= n) return;
  const float4v a = *(const float4v*)(in + i);
  const float4v b = *(const float4v*)(in + i + 4);
  short8 h;
  h[0] = f2bf(a[0]); h[1] = f2bf(a[1]); h[2] = f2bf(a[2]); h[3] = f2bf(a[3]);
  h[4] = f2bf(b[0]); h[5] = f2bf(b[1]); h[6] = f2bf(b[2]); h[7] = f2bf(b[3]);
  *(short8*)(out + i) = h;
}

// ---------------------------------------------------------------------------
// Kernel 3: 256x256 bf16 GEMM + bias + silu + mul. 8 waves (2M x 4N), BK=64,
// 128 KiB LDS double-buffer, swizzled, 1 barrier/tile (r13: 439->420 us).
// ROUND-14: ONE variable vs r13: setprio(1)/(0) around the MFMA half-blocks.
// Mechanism: the tile-top read burst serializes through the LDS pipe, so
// waves reach their MFMA clusters at staggered times (progress diversity) —
// the regime where setprio pays (m191); r3's lockstep null no longer applies.
// ---------------------------------------------------------------------------
__global__ __launch_bounds__(512, 2)
void gemm256_silu_mul_kernel(const short* __restrict__ A,   // [M,K] bf16
                             const short* __restrict__ Bt,  // [N,K] bf16
                             const float* __restrict__ bias,
                             const float* __restrict__ mulp,
                             float*       __restrict__ out,
                             int M, int N, int K)
{
  __shared__ short L[2][2][16384];   // [buf][A|B][32 subtiles * 512] = 128 KiB

  const int tid  = threadIdx.x;
  const int lane = tid & 63;
  const int wave = tid >> 6;   // 0..7
  const int wm   = wave >> 2;  // 0..1 : row half
  const int wn   = wave & 3;   // 0..3 : col quarter

  // bijective XCD-aware swizzle of the linear block id (m204 variant)
  const int nwg = gridDim.x;
  const int q8 = nwg >> 3, r8 = nwg & 7;
  const int xcd = blockIdx.x & 7, sub = blockIdx.x >> 3;
  const int swz = (xcd < r8 ? xcd * (q8 + 1) : r8 * (q8 + 1) + (xcd - r8) * q8) + sub;
  const int nbx = N >> 8;
  const int bx = swz % nbx, by = swz / nbx;
  const int m0 = by << 8, n0 = bx << 8;

  const short* Ab = A  + (size_t)m0 * K;
  const short* Bb = Bt + (size_t)n0 * K;

  // staging source geometry (pre-swizzled global column; linear LDS dest)
  const int srow = lane >> 2;                               // 0..15 subtile row
  const int scol = (((lane & 3) ^ ((lane & 32) >> 4))) * 8; // pre-swizzled k slot
  // fragment-read geometry (swizzled ds_read address)
  const int fm = lane & 15;
  const int ko = ((lane >> 4) * 8) ^ ((fm & 8) ? 16 : 0);   // k elem offset

  // staging group ownership (16-row groups, 2 subtiles each)
  const int BG0 = wave * 2;
  const int BG1 = wave * 2 + 1;
  const int AEg = (wave & 3) + (wave >> 2) * 8;  // A groups {0-3,8-11}
  const int ALg = AEg + 4;                       // A groups {4-7,12-15}

  float4v acc[8][4];
  #pragma unroll
  for (int i = 0; i < 8; ++i)
    #pragma unroll
    for (int j = 0; j < 4; ++j)
      acc[i][j] = (float4v){0.f, 0.f, 0.f, 0.f};

  const int NT = K >> 6;

  auto stage2 = [&](int buf, int ab, int g, const short* __restrict__ base, int kk) {
    #pragma unroll
    for (int ks = 0; ks < 2; ++ks)
      gl_lds16(base + (size_t)(g * 16 + srow) * K + kk + ks * 32 + scol,
               &L[buf][ab][(g * 2 + ks) * 512]);
  };

  // prologue: tile 0 -> buf 0
  stage2(0, 1, BG0, Bb, 0);
  stage2(0, 1, BG1, Bb, 0);
  stage2(0, 0, AEg, Ab, 0);
  stage2(0, 0, ALg, Ab, 0);
  __syncthreads();

  for (int t = 0; t < NT; ++t) {
    const int cur = t & 1;
    const int nxt = cur ^ 1;

    // stage t+1 into the other buffer (in flight across the whole tile body)
    if (t + 1 < NT) {
      const int kk1 = (t + 1) << 6;
      stage2(nxt, 1, BG0, Bb, kk1);
      stage2(nxt, 1, BG1, Bb, kk1);
      stage2(nxt, 0, AEg, Ab, kk1);
      stage2(nxt, 0, ALg, Ab, kk1);
    }

    // compute: all 24 fragment reads + 64 MFMAs, compiler-scheduled
    short8 af[4][2], bf[4][2];
    #pragma unroll
    for (int j = 0; j < 4; ++j)
      #pragma unroll
      for (int ks = 0; ks < 2; ++ks)
        bf[j][ks] = *(const short8*)(
            &L[cur][1][((wn * 4 + j) * 2 + ks) * 512 + fm * 32 + ko]);

    #pragma unroll
    for (int i = 0; i < 4; ++i)
      #pragma unroll
      for (int ks = 0; ks < 2; ++ks)
        af[i][ks] = *(const short8*)(
            &L[cur][0][((wm * 8 + i) * 2 + ks) * 512 + fm * 32 + ko]);
    __builtin_amdgcn_s_setprio(1);
    #pragma unroll
    for (int i = 0; i < 4; ++i)
      #pragma unroll
      for (int j = 0; j < 4; ++j)
        #pragma unroll
        for (int ks = 0; ks < 2; ++ks)
          acc[i][j] = __builtin_amdgcn_mfma_f32_16x16x32_bf16(
              af[i][ks], bf[j][ks], acc[i][j], 0, 0, 0);
    __builtin_amdgcn_s_setprio(0);

    #pragma unroll
    for (int i = 0; i < 4; ++i)
      #pragma unroll
      for (int ks = 0; ks < 2; ++ks)
        af[i][ks] = *(const short8*)(
            &L[cur][0][((wm * 8 + 4 + i) * 2 + ks) * 512 + fm * 32 + ko]);
    __builtin_amdgcn_s_setprio(1);
    #pragma unroll
    for (int i = 0; i < 4; ++i)
      #pragma unroll
      for (int j = 0; j < 4; ++j)
        #pragma unroll
        for (int ks = 0; ks < 2; ++ks)
          acc[4 + i][j] = __builtin_amdgcn_mfma_f32_16x16x32_bf16(
              af[i][ks], bf[j][ks], acc[4 + i][j], 0, 0, 0);
    __builtin_amdgcn_s_setprio(0);

    // single barrier per tile: drains gl_lds (vmcnt) + ds reads (lgkm),
    // fences LDS motion, and releases nxt for the next iteration's stage.
    __syncthreads();
  }

  // epilogue: bias + silu + mul
  const int cn  = lane & 15;
  const int cr4 = (lane >> 4) * 4;
  #pragma unroll
  for (int mt = 0; mt < 8; ++mt) {
    #pragma unroll
    for (int nt = 0; nt < 4; ++nt) {
      const int n  = n0 + wn * 64 + nt * 16 + cn;
      const float bn = bias[n];
      #pragma unroll
      for (int i = 0; i < 4; ++i) {
        const int m = m0 + wm * 128 + mt * 16 + cr4 + i;
        float x = acc[mt][nt][i] + bn;
        float s = x / (1.0f + __expf(-x));
        out[(size_t)m * N + n] = s * mulp[(size_t)m * N + n];
      }
    }
  }
}

// ---------------------------------------------------------------------------
// Kernel 3 (fallback shapes): 128x128 m97-structure GEMM
// ---------------------------------------------------------------------------
__global__ __launch_bounds__(256, 2)
void gemm_silu_mul_kernel(const short* __restrict__ A,
                          const short* __restrict__ Bt,
                          const float* __restrict__ bias,
                          const float* __restrict__ mulp,
                          float*       __restrict__ out,
                          int M, int N, int K)
{
  __shared__ short As[128 * 64];
  __shared__ short Bs[128 * 64];

  const int tid  = threadIdx.x;
  const int lane = tid & 63;
  const int wave = tid >> 6;
  const int wr = (wave >> 1) * 64;
  const int wc = (wave & 1) * 64;
  const int m0 = blockIdx.y * 128;
  const int n0 = blockIdx.x * 128;

  float4v acc[4][4];
  #pragma unroll
  for (int i = 0; i < 4; ++i)
    #pragma unroll
    for (int j = 0; j < 4; ++j)
      acc[i][j] = (float4v){0.f, 0.f, 0.f, 0.f};

  const int fm = lane & 15;
  const int fk = (lane >> 4) * 8;
  const int srow = lane >> 3;
  const int scol = (lane & 7) * 8;

  for (int k0 = 0; k0 < K; k0 += 64) {
    #pragma unroll
    for (int c = 0; c < 4; ++c) {
      const int chunk = wave * 4 + c;
      const int row   = chunk * 8 + srow;
      gl_lds16(A  + (size_t)(m0 + row) * K + k0 + scol, &As[chunk * 512]);
      gl_lds16(Bt + (size_t)(n0 + row) * K + k0 + scol, &Bs[chunk * 512]);
    }
    __syncthreads();

    #pragma unroll
    for (int ks = 0; ks < 64; ks += 32) {
      short8 a[4], b[4];
      #pragma unroll
      for (int mt = 0; mt < 4; ++mt)
        a[mt] = *(const short8*)(&As[(wr + mt * 16 + fm) * 64 + ks + fk]);
      #pragma unroll
      for (int nt = 0; nt < 4; ++nt)
        b[nt] = *(const short8*)(&Bs[(wc + nt * 16 + fm) * 64 + ks + fk]);
      #pragma unroll
      for (int mt = 0; mt < 4; ++mt)
        #pragma unroll
        for (int nt = 0; nt < 4; ++nt)
          acc[mt][nt] = __builtin_amdgcn_mfma_f32_16x16x32_bf16(a[mt], b[nt], acc[mt][nt], 0, 0, 0);
    }
    __syncthreads();
  }

  const int cn = lane & 15;
  const int cr = (lane >> 4) * 4;
  #pragma unroll
  for (int mt = 0; mt < 4; ++mt) {
    #pragma unroll
    for (int nt = 0; nt < 4; ++nt) {
      const int n  = n0 + wc + nt * 16 + cn;
      const float bn = bias[n];
      #pragma unroll
      for (int i = 0; i < 4; ++i) {
        const int m = m0 + wr + mt * 16 + cr + i;
        float x = acc[mt][nt][i] + bn;
        float s = x / (1.0f + __expf(-x));
        out[(size_t)m * N + n] = s * mulp[(size_t)m * N + n];
      }
    }
  }
}

// ---------------------------------------------------------------------------
// Fallback: round-1 fused kernel (used only if ws_size is too small)
// ---------------------------------------------------------------------------
#define BM 128
#define BN 128
#define BK 64
#define LDA 72
#define LDB 72

__global__ __launch_bounds__(256, 2)
void woq_silu_mul_kernel(const float* __restrict__ inp, const int* __restrict__ qw,
                         const float* __restrict__ scales, const int* __restrict__ qzeros,
                         const float* __restrict__ bias, const float* __restrict__ mulp,
                         float* __restrict__ out, int M, int N, int K, int G)
{
  __shared__ short As[BM * LDA];
  __shared__ short Bs[BN * LDB];
  const int tid  = threadIdx.x;
  const int lane = tid & 63;
  const int wave = tid >> 6;
  const int wr = (wave >> 1) * 64;
  const int wc = (wave & 1) * 64;
  const int m0 = blockIdx.y * BM;
  const int n0 = blockIdx.x * BN;
  const int N8 = N >> 3;
  float4v acc[4][4];
  #pragma unroll
  for (int i = 0; i < 4; ++i)
    #pragma unroll
    for (int j = 0; j < 4; ++j)
      acc[i][j] = (float4v){0.f, 0.f, 0.f, 0.f};
  const int n8l  = tid >> 4;
  const int kloc = (tid & 15) * 4;
  const int fm = lane & 15;
  const int fk = (lane >> 4) * 8;
  for (int k0 = 0; k0 < K; k0 += BK) {
    #pragma unroll
    for (int i = 0; i < 8; ++i) {
      int f = tid + i * 256;
      int row = f >> 4;
      int col = (f & 15) * 4;
      float4v a4 = *(const float4v*)(inp + (size_t)(m0 + row) * K + k0 + col);
      short4v h;
      h[0] = f2bf(a4[0]); h[1] = f2bf(a4[1]); h[2] = f2bf(a4[2]); h[3] = f2bf(a4[3]);
      *(short4v*)(&As[row * LDA + col]) = h;
    }
    {
      const int g = k0 / G;
      const int n8g = (n0 >> 3) + n8l;
      const int zw = qzeros[(size_t)g * N8 + n8g];
      const float4v s0 = *(const float4v*)(scales + (size_t)g * N + n0 + n8l * 8);
      const float4v s1 = *(const float4v*)(scales + (size_t)g * N + n0 + n8l * 8 + 4);
      float sc[8] = {s0[0], s0[1], s0[2], s0[3], s1[0], s1[1], s1[2], s1[3]};
      int w[4];
      #pragma unroll
      for (int kk = 0; kk < 4; ++kk)
        w[kk] = qw[(size_t)(k0 + kloc + kk) * N8 + n8g];
      #pragma unroll
      for (int j = 0; j < 8; ++j) {
        const float zj = (float)((zw >> (4 * j)) & 0xF);
        const float sj = sc[j];
        short4v h;
        #pragma unroll
        for (int kk = 0; kk < 4; ++kk) {
          int q = (w[kk] >> (4 * j)) & 0xF;
          h[kk] = f2bf(((float)q - zj) * sj);
        }
        *(short4v*)(&Bs[(n8l * 8 + j) * LDB + kloc]) = h;
      }
    }
    __syncthreads();
    #pragma unroll
    for (int ks = 0; ks < BK; ks += 32) {
      short8 a[4], b[4];
      #pragma unroll
      for (int mt = 0; mt < 4; ++mt)
        a[mt] = *(const short8*)(&As[(wr + mt * 16 + fm) * LDA + ks + fk]);
      #pragma unroll
      for (int nt = 0; nt < 4; ++nt)
        b[nt] = *(const short8*)(&Bs[(wc + nt * 16 + fm) * LDB + ks + fk]);
      #pragma unroll
      for (int mt = 0; mt < 4; ++mt)
        #pragma unroll
        for (int nt = 0; nt < 4; ++nt)
          acc[mt][nt] = __builtin_amdgcn_mfma_f32_16x16x32_bf16(a[mt], b[nt], acc[mt][nt], 0, 0, 0);
    }
    __syncthreads();
  }
  const int cn = lane & 15;
  const int cr = (lane >> 4) * 4;
  #pragma unroll
  for (int mt = 0; mt < 4; ++mt) {
    #pragma unroll
    for (int nt = 0; nt < 4; ++nt) {
      const int n = n0 + wc + nt * 16 + cn;
      const float bn = bias[n];
      #pragma unroll
      for (int i = 0; i < 4; ++i) {
        const int m = m0 + wr + mt * 16 + cr + i;
        float x = acc[mt][nt][i] + bn;
        float s = x / (1.0f + __expf(-x));
        out[(size_t)m * N + n] = s * mulp[(size_t)m * N + n];
      }
    }
  }
}

extern "C" void kernel_launch(void* const* d_in, const int* in_sizes, int n_in,
                              void* d_out, int out_size, void* d_ws, size_t ws_size,
                              hipStream_t stream) {
  const float* inp    = (const float*)d_in[0];
  const int*   qw     = (const int*)d_in[1];
  const float* scales = (const float*)d_in[2];
  const int*   qzeros = (const int*)d_in[3];
  const float* bias   = (const float*)d_in[4];
  const float* mulp   = (const float*)d_in[5];
  float*       out    = (float*)d_out;

  const int N = in_sizes[4];
  const int K = (int)(((long long)in_sizes[1] * 8) / N);
  const int M = (int)((long long)in_sizes[0] / K);
  const int G = K / (in_sizes[2] / N);

  const size_t btBytes = (size_t)N * K * sizeof(short);
  const size_t aBytes  = (size_t)M * K * sizeof(short);

  if (ws_size >= btBytes + aBytes) {
    short* Bt  = (short*)d_ws;
    short* Abf = (short*)((char*)d_ws + btBytes);
    const long long nA = (long long)M * K;

    const bool dqOk = (N & 255) == 0 && (K & 63) == 0 && G >= 64 && (G & 63) == 0
                      && (nA & 7) == 0;
    if (dqOk) {
      const int nDq = (K / 64) * (N / 256);
      const int nAc = (int)((nA / 8 + 255) / 256);
      prep_kernel<<<dim3((unsigned)(nDq + nAc)), dim3(256), 0, stream>>>(
          qw, scales, qzeros, Bt, inp, Abf, K, N, G, nDq, nA);
    } else {
      dim3 dq_grid(K / 64, (N / 8) / 16);
      dequant_kernel_v0<<<dq_grid, dim3(256), 0, stream>>>(qw, scales, qzeros, Bt, K, N, G);
      aconv_kernel<<<dim3((unsigned)((nA / 8 + 255) / 256)), dim3(256), 0, stream>>>(inp, Abf, nA);
    }

    if ((M & 255) == 0 && (N & 255) == 0 && (K & 63) == 0) {
      dim3 grid((unsigned)((N >> 8) * (M >> 8)));
      gemm256_silu_mul_kernel<<<grid, dim3(512), 0, stream>>>(Abf, Bt, bias, mulp, out, M, N, K);
    } else {
      dim3 grid(N / 128, M / 128);
      gemm_silu_mul_kernel<<<grid, dim3(256), 0, stream>>>(Abf, Bt, bias, mulp, out, M, N, K);
    }
  } else {
    dim3 grid(N / BN, M / BM);
    woq_silu_mul_kernel<<<grid, dim3(256), 0, stream>>>(inp, qw, scales, qzeros,
                                                        bias, mulp, out, M, N, K, G);
  }
}

// Round 15
// 687.800 us; speedup vs baseline: 1.0153x; 1.0135x over previous
//
#include <hip/hip_runtime.h>
#include <hip/hip_bf16.h>

typedef __attribute__((ext_vector_type(8))) short short8;
typedef __attribute__((ext_vector_type(4))) short short4v;
typedef __attribute__((ext_vector_type(4))) float float4v;

__device__ __forceinline__ short f2bf(float f) {
  union { float f; unsigned u; } v; v.f = f;
  unsigned r = v.u + 0x7fffu + ((v.u >> 16) & 1u);  // RNE
  return (short)(r >> 16);
}

typedef const __attribute__((address_space(1))) unsigned int* as1_u32p;
typedef __attribute__((address_space(3))) unsigned int* as3_u32p;

__device__ __forceinline__ void gl_lds16(const void* g, void* l) {
  // async global->LDS, 16B/lane, dest = wave-uniform base + lane*16
  __builtin_amdgcn_global_load_lds((as1_u32p)g, (as3_u32p)l, 16, 0, 0);
}

// ---------------------------------------------------------------------------
// Kernel P: fused prep = dequant int4->bf16 W^T [N,K] + A fp32->bf16.
// ---------------------------------------------------------------------------
__global__ __launch_bounds__(256, 4)
void prep_kernel(const int* __restrict__ qw,      // [K, N/8]
                 const float* __restrict__ scales,// [K/G, N]
                 const int* __restrict__ qzeros,  // [K/G, N/8]
                 short* __restrict__ Bt,          // [N, K] bf16 out
                 const float* __restrict__ inp,   // [M, K] fp32
                 short* __restrict__ Abf,         // [M, K] bf16 out
                 int K, int N, int G, int nDq, long long nA)
{
  constexpr int KP = 72;                 // padded k-stride (shorts)
  __shared__ short Ls[256 * KP];         // ~36 KB

  if ((int)blockIdx.x >= nDq) {
    // ---- aconv part ----
    const long long i =
        (((long long)blockIdx.x - nDq) * blockDim.x + threadIdx.x) * 8;
    if (i >= nA) return;
    const float4v a = *(const float4v*)(inp + i);
    const float4v b = *(const float4v*)(inp + i + 4);
    short8 h;
    h[0] = f2bf(a[0]); h[1] = f2bf(a[1]); h[2] = f2bf(a[2]); h[3] = f2bf(a[3]);
    h[4] = f2bf(b[0]); h[5] = f2bf(b[1]); h[6] = f2bf(b[2]); h[7] = f2bf(b[3]);
    *(short8*)(Abf + i) = h;
    return;
  }

  // ---- dequant part ----
  const int KB  = K >> 6;
  const int N8  = N >> 3;
  const int k0  = ((int)blockIdx.x % KB) * 64;
  const int nb  = (int)blockIdx.x / KB;
  const int n0  = nb * 256;
  const int n80 = nb * 32;
  const int g   = k0 / G;
  const int t   = threadIdx.x;
  const int kloc = t >> 3;               // 0..31
  const int w4   = (t & 7) * 4;          // int4-word offset 0..28

  const int4 z4 = *(const int4*)(qzeros + (size_t)g * N8 + n80 + w4);
  const int za[4] = {z4.x, z4.y, z4.z, z4.w};
  float sc[32];
  #pragma unroll
  for (int ii = 0; ii < 8; ++ii)
    *(float4v*)(sc + ii * 4) =
        *(const float4v*)(scales + (size_t)g * N + n0 + w4 * 8 + ii * 4);

  #pragma unroll
  for (int kh = 0; kh < 2; ++kh) {
    const int k = kloc + kh * 32;
    const int4 q4 = *(const int4*)(qw + (size_t)(k0 + k) * N8 + n80 + w4);
    const int qa[4] = {q4.x, q4.y, q4.z, q4.w};
    #pragma unroll
    for (int ii = 0; ii < 4; ++ii) {
      #pragma unroll
      for (int j = 0; j < 8; ++j) {
        const float z = (float)((za[ii] >> (4 * j)) & 0xF);
        const float q = (float)((qa[ii] >> (4 * j)) & 0xF);
        Ls[(w4 * 8 + ii * 8 + j) * KP + k] = f2bf((q - z) * sc[ii * 8 + j]);
      }
    }
  }
  __syncthreads();

  #pragma unroll
  for (int it = 0; it < 8; ++it) {
    const int idx = t + it * 256;        // 0..2047
    const int row = idx >> 3;            // 0..255
    const int ch  = (idx & 7) * 8;       // k element offset
    const short8 v = *(const short8*)(&Ls[row * KP + ch]);
    *(short8*)(Bt + (size_t)(n0 + row) * K + k0 + ch) = v;
  }
}

// ---------------------------------------------------------------------------
// Fallback prep kernels (odd shapes)
// ---------------------------------------------------------------------------
__global__ __launch_bounds__(256, 2)
void dequant_kernel_v0(const int* __restrict__ qw,
                       const float* __restrict__ scales,
                       const int* __restrict__ qzeros,
                       short* __restrict__ Bt,
                       int K, int N, int G)
{
  __shared__ short Ls[128 * 64];   // [n_local][k_local]
  const int N8  = N >> 3;
  const int k0  = blockIdx.x * 64;
  const int n80 = blockIdx.y * 16;
  const int g   = k0 / G;
  const int tid  = threadIdx.x;
  const int lane = tid & 63;
  const int w    = tid >> 6;

  const int4 q4 = *(const int4*)(qw + (size_t)(k0 + lane) * N8 + n80 + w * 4);
  const int4 z4 = *(const int4*)(qzeros + (size_t)g * N8 + n80 + w * 4);
  const int qa[4] = {q4.x, q4.y, q4.z, q4.w};
  const int za[4] = {z4.x, z4.y, z4.z, z4.w};

  #pragma unroll
  for (int it = 0; it < 4; ++it) {
    const int n8l = w * 4 + it;
    const float4v s0 = *(const float4v*)(scales + (size_t)g * N + (n80 + n8l) * 8);
    const float4v s1 = *(const float4v*)(scales + (size_t)g * N + (n80 + n8l) * 8 + 4);
    const float sc[8] = {s0[0], s0[1], s0[2], s0[3], s1[0], s1[1], s1[2], s1[3]};
    const int wq = qa[it], wz = za[it];
    #pragma unroll
    for (int j = 0; j < 8; ++j) {
      const float z = (float)((wz >> (4 * j)) & 0xF);
      const float q = (float)((wq >> (4 * j)) & 0xF);
      Ls[(n8l * 8 + j) * 64 + lane] = f2bf((q - z) * sc[j]);
    }
  }
  __syncthreads();

  #pragma unroll
  for (int it = 0; it < 4; ++it) {
    const int c   = tid + it * 256;
    const int row = c >> 3;
    const int off = (c & 7) * 8;
    const short8 v = *(const short8*)(&Ls[row * 64 + off]);
    *(short8*)(Bt + (size_t)(n80 * 8 + row) * K + k0 + off) = v;
  }
}

__global__ __launch_bounds__(256, 4)
void aconv_kernel(const float* __restrict__ in, short* __restrict__ out, long long n)
{
  const long long i = ((long long)blockIdx.x * blockDim.x + threadIdx.x) * 8;
  if (i >= n) return;
  const float4v a = *(const float4v*)(in + i);
  const float4v b = *(const float4v*)(in + i + 4);
  short8 h;
  h[0] = f2bf(a[0]); h[1] = f2bf(a[1]); h[2] = f2bf(a[2]); h[3] = f2bf(a[3]);
  h[4] = f2bf(b[0]); h[5] = f2bf(b[1]); h[6] = f2bf(b[2]); h[7] = f2bf(b[3]);
  *(short8*)(out + i) = h;
}

// ---------------------------------------------------------------------------
// Kernel 3 (FINAL = round-13 config, best measured: gemm 419.8 us):
// 256x256 bf16 GEMM + bias + silu + mul. 8 waves (2M x 4N), BK=64,
// 128 KiB LDS double-buffer, st_16x32-style swizzle (pre-swizzled global
// source + swizzled ds_read), XCD-aware bijective block swizzle, ONE
// __syncthreads per K-tile (r13: 439->420 us, MfmaUtil 37->39.7, VGPR 96).
// r14's setprio was null-to-negative (m190 regime) and is reverted.
// Session-closed axes: 7 sync schedules (433-468 us band), occupancy
// (register-capped: acc 128 AGPR + ~96 VGPR => 1 block/CU), L2 mapping
// (FETCH -33%, time-neutral), LDS conflicts (0), prep variants, launch
// fusion, in-GEMM dequant (qw stride kills it). Measured plateau:
// ~880 TF = 35% dense peak for this plain-HIP structure.
// ---------------------------------------------------------------------------
__global__ __launch_bounds__(512, 2)
void gemm256_silu_mul_kernel(const short* __restrict__ A,   // [M,K] bf16
                             const short* __restrict__ Bt,  // [N,K] bf16
                             const float* __restrict__ bias,
                             const float* __restrict__ mulp,
                             float*       __restrict__ out,
                             int M, int N, int K)
{
  __shared__ short L[2][2][16384];   // [buf][A|B][32 subtiles * 512] = 128 KiB

  const int tid  = threadIdx.x;
  const int lane = tid & 63;
  const int wave = tid >> 6;   // 0..7
  const int wm   = wave >> 2;  // 0..1 : row half
  const int wn   = wave & 3;   // 0..3 : col quarter

  // bijective XCD-aware swizzle of the linear block id (m204 variant)
  const int nwg = gridDim.x;
  const int q8 = nwg >> 3, r8 = nwg & 7;
  const int xcd = blockIdx.x & 7, sub = blockIdx.x >> 3;
  const int swz = (xcd < r8 ? xcd * (q8 + 1) : r8 * (q8 + 1) + (xcd - r8) * q8) + sub;
  const int nbx = N >> 8;
  const int bx = swz % nbx, by = swz / nbx;
  const int m0 = by << 8, n0 = bx << 8;

  const short* Ab = A  + (size_t)m0 * K;
  const short* Bb = Bt + (size_t)n0 * K;

  // staging source geometry (pre-swizzled global column; linear LDS dest)
  const int srow = lane >> 2;                               // 0..15 subtile row
  const int scol = (((lane & 3) ^ ((lane & 32) >> 4))) * 8; // pre-swizzled k slot
  // fragment-read geometry (swizzled ds_read address)
  const int fm = lane & 15;
  const int ko = ((lane >> 4) * 8) ^ ((fm & 8) ? 16 : 0);   // k elem offset

  // staging group ownership (16-row groups, 2 subtiles each)
  const int BG0 = wave * 2;
  const int BG1 = wave * 2 + 1;
  const int AEg = (wave & 3) + (wave >> 2) * 8;  // A groups {0-3,8-11}
  const int ALg = AEg + 4;                       // A groups {4-7,12-15}

  float4v acc[8][4];
  #pragma unroll
  for (int i = 0; i < 8; ++i)
    #pragma unroll
    for (int j = 0; j < 4; ++j)
      acc[i][j] = (float4v){0.f, 0.f, 0.f, 0.f};

  const int NT = K >> 6;

  auto stage2 = [&](int buf, int ab, int g, const short* __restrict__ base, int kk) {
    #pragma unroll
    for (int ks = 0; ks < 2; ++ks)
      gl_lds16(base + (size_t)(g * 16 + srow) * K + kk + ks * 32 + scol,
               &L[buf][ab][(g * 2 + ks) * 512]);
  };

  // prologue: tile 0 -> buf 0
  stage2(0, 1, BG0, Bb, 0);
  stage2(0, 1, BG1, Bb, 0);
  stage2(0, 0, AEg, Ab, 0);
  stage2(0, 0, ALg, Ab, 0);
  __syncthreads();

  for (int t = 0; t < NT; ++t) {
    const int cur = t & 1;
    const int nxt = cur ^ 1;

    // stage t+1 into the other buffer (in flight across the whole tile body)
    if (t + 1 < NT) {
      const int kk1 = (t + 1) << 6;
      stage2(nxt, 1, BG0, Bb, kk1);
      stage2(nxt, 1, BG1, Bb, kk1);
      stage2(nxt, 0, AEg, Ab, kk1);
      stage2(nxt, 0, ALg, Ab, kk1);
    }

    // compute: all 24 fragment reads + 64 MFMAs, compiler-scheduled
    short8 af[4][2], bf[4][2];
    #pragma unroll
    for (int j = 0; j < 4; ++j)
      #pragma unroll
      for (int ks = 0; ks < 2; ++ks)
        bf[j][ks] = *(const short8*)(
            &L[cur][1][((wn * 4 + j) * 2 + ks) * 512 + fm * 32 + ko]);

    #pragma unroll
    for (int i = 0; i < 4; ++i)
      #pragma unroll
      for (int ks = 0; ks < 2; ++ks)
        af[i][ks] = *(const short8*)(
            &L[cur][0][((wm * 8 + i) * 2 + ks) * 512 + fm * 32 + ko]);
    #pragma unroll
    for (int i = 0; i < 4; ++i)
      #pragma unroll
      for (int j = 0; j < 4; ++j)
        #pragma unroll
        for (int ks = 0; ks < 2; ++ks)
          acc[i][j] = __builtin_amdgcn_mfma_f32_16x16x32_bf16(
              af[i][ks], bf[j][ks], acc[i][j], 0, 0, 0);

    #pragma unroll
    for (int i = 0; i < 4; ++i)
      #pragma unroll
      for (int ks = 0; ks < 2; ++ks)
        af[i][ks] = *(const short8*)(
            &L[cur][0][((wm * 8 + 4 + i) * 2 + ks) * 512 + fm * 32 + ko]);
    #pragma unroll
    for (int i = 0; i < 4; ++i)
      #pragma unroll
      for (int j = 0; j < 4; ++j)
        #pragma unroll
        for (int ks = 0; ks < 2; ++ks)
          acc[4 + i][j] = __builtin_amdgcn_mfma_f32_16x16x32_bf16(
              af[i][ks], bf[j][ks], acc[4 + i][j], 0, 0, 0);

    // single barrier per tile: drains gl_lds (vmcnt) + ds reads (lgkm),
    // fences LDS motion, and releases nxt for the next iteration's stage.
    __syncthreads();
  }

  // epilogue: bias + silu + mul
  const int cn  = lane & 15;
  const int cr4 = (lane >> 4) * 4;
  #pragma unroll
  for (int mt = 0; mt < 8; ++mt) {
    #pragma unroll
    for (int nt = 0; nt < 4; ++nt) {
      const int n  = n0 + wn * 64 + nt * 16 + cn;
      const float bn = bias[n];
      #pragma unroll
      for (int i = 0; i < 4; ++i) {
        const int m = m0 + wm * 128 + mt * 16 + cr4 + i;
        float x = acc[mt][nt][i] + bn;
        float s = x / (1.0f + __expf(-x));
        out[(size_t)m * N + n] = s * mulp[(size_t)m * N + n];
      }
    }
  }
}

// ---------------------------------------------------------------------------
// Kernel 3 (fallback shapes): 128x128 m97-structure GEMM
// ---------------------------------------------------------------------------
__global__ __launch_bounds__(256, 2)
void gemm_silu_mul_kernel(const short* __restrict__ A,
                          const short* __restrict__ Bt,
                          const float* __restrict__ bias,
                          const float* __restrict__ mulp,
                          float*       __restrict__ out,
                          int M, int N, int K)
{
  __shared__ short As[128 * 64];
  __shared__ short Bs[128 * 64];

  const int tid  = threadIdx.x;
  const int lane = tid & 63;
  const int wave = tid >> 6;
  const int wr = (wave >> 1) * 64;
  const int wc = (wave & 1) * 64;
  const int m0 = blockIdx.y * 128;
  const int n0 = blockIdx.x * 128;

  float4v acc[4][4];
  #pragma unroll
  for (int i = 0; i < 4; ++i)
    #pragma unroll
    for (int j = 0; j < 4; ++j)
      acc[i][j] = (float4v){0.f, 0.f, 0.f, 0.f};

  const int fm = lane & 15;
  const int fk = (lane >> 4) * 8;
  const int srow = lane >> 3;
  const int scol = (lane & 7) * 8;

  for (int k0 = 0; k0 < K; k0 += 64) {
    #pragma unroll
    for (int c = 0; c < 4; ++c) {
      const int chunk = wave * 4 + c;
      const int row   = chunk * 8 + srow;
      gl_lds16(A  + (size_t)(m0 + row) * K + k0 + scol, &As[chunk * 512]);
      gl_lds16(Bt + (size_t)(n0 + row) * K + k0 + scol, &Bs[chunk * 512]);
    }
    __syncthreads();

    #pragma unroll
    for (int ks = 0; ks < 64; ks += 32) {
      short8 a[4], b[4];
      #pragma unroll
      for (int mt = 0; mt < 4; ++mt)
        a[mt] = *(const short8*)(&As[(wr + mt * 16 + fm) * 64 + ks + fk]);
      #pragma unroll
      for (int nt = 0; nt < 4; ++nt)
        b[nt] = *(const short8*)(&Bs[(wc + nt * 16 + fm) * 64 + ks + fk]);
      #pragma unroll
      for (int mt = 0; mt < 4; ++mt)
        #pragma unroll
        for (int nt = 0; nt < 4; ++nt)
          acc[mt][nt] = __builtin_amdgcn_mfma_f32_16x16x32_bf16(a[mt], b[nt], acc[mt][nt], 0, 0, 0);
    }
    __syncthreads();
  }

  const int cn = lane & 15;
  const int cr = (lane >> 4) * 4;
  #pragma unroll
  for (int mt = 0; mt < 4; ++mt) {
    #pragma unroll
    for (int nt = 0; nt < 4; ++nt) {
      const int n  = n0 + wc + nt * 16 + cn;
      const float bn = bias[n];
      #pragma unroll
      for (int i = 0; i < 4; ++i) {
        const int m = m0 + wr + mt * 16 + cr + i;
        float x = acc[mt][nt][i] + bn;
        float s = x / (1.0f + __expf(-x));
        out[(size_t)m * N + n] = s * mulp[(size_t)m * N + n];
      }
    }
  }
}

// ---------------------------------------------------------------------------
// Fallback: round-1 fused kernel (used only if ws_size is too small)
// ---------------------------------------------------------------------------
#define BM 128
#define BN 128
#define BK 64
#define LDA 72
#define LDB 72

__global__ __launch_bounds__(256, 2)
void woq_silu_mul_kernel(const float* __restrict__ inp, const int* __restrict__ qw,
                         const float* __restrict__ scales, const int* __restrict__ qzeros,
                         const float* __restrict__ bias, const float* __restrict__ mulp,
                         float* __restrict__ out, int M, int N, int K, int G)
{
  __shared__ short As[BM * LDA];
  __shared__ short Bs[BN * LDB];
  const int tid  = threadIdx.x;
  const int lane = tid & 63;
  const int wave = tid >> 6;
  const int wr = (wave >> 1) * 64;
  const int wc = (wave & 1) * 64;
  const int m0 = blockIdx.y * BM;
  const int n0 = blockIdx.x * BN;
  const int N8 = N >> 3;
  float4v acc[4][4];
  #pragma unroll
  for (int i = 0; i < 4; ++i)
    #pragma unroll
    for (int j = 0; j < 4; ++j)
      acc[i][j] = (float4v){0.f, 0.f, 0.f, 0.f};
  const int n8l  = tid >> 4;
  const int kloc = (tid & 15) * 4;
  const int fm = lane & 15;
  const int fk = (lane >> 4) * 8;
  for (int k0 = 0; k0 < K; k0 += BK) {
    #pragma unroll
    for (int i = 0; i < 8; ++i) {
      int f = tid + i * 256;
      int row = f >> 4;
      int col = (f & 15) * 4;
      float4v a4 = *(const float4v*)(inp + (size_t)(m0 + row) * K + k0 + col);
      short4v h;
      h[0] = f2bf(a4[0]); h[1] = f2bf(a4[1]); h[2] = f2bf(a4[2]); h[3] = f2bf(a4[3]);
      *(short4v*)(&As[row * LDA + col]) = h;
    }
    {
      const int g = k0 / G;
      const int n8g = (n0 >> 3) + n8l;
      const int zw = qzeros[(size_t)g * N8 + n8g];
      const float4v s0 = *(const float4v*)(scales + (size_t)g * N + n0 + n8l * 8);
      const float4v s1 = *(const float4v*)(scales + (size_t)g * N + n0 + n8l * 8 + 4);
      float sc[8] = {s0[0], s0[1], s0[2], s0[3], s1[0], s1[1], s1[2], s1[3]};
      int w[4];
      #pragma unroll
      for (int kk = 0; kk < 4; ++kk)
        w[kk] = qw[(size_t)(k0 + kloc + kk) * N8 + n8g];
      #pragma unroll
      for (int j = 0; j < 8; ++j) {
        const float zj = (float)((zw >> (4 * j)) & 0xF);
        const float sj = sc[j];
        short4v h;
        #pragma unroll
        for (int kk = 0; kk < 4; ++kk) {
          int q = (w[kk] >> (4 * j)) & 0xF;
          h[kk] = f2bf(((float)q - zj) * sj);
        }
        *(short4v*)(&Bs[(n8l * 8 + j) * LDB + kloc]) = h;
      }
    }
    __syncthreads();
    #pragma unroll
    for (int ks = 0; ks < BK; ks += 32) {
      short8 a[4], b[4];
      #pragma unroll
      for (int mt = 0; mt < 4; ++mt)
        a[mt] = *(const short8*)(&As[(wr + mt * 16 + fm) * LDA + ks + fk]);
      #pragma unroll
      for (int nt = 0; nt < 4; ++nt)
        b[nt] = *(const short8*)(&Bs[(wc + nt * 16 + fm) * LDB + ks + fk]);
      #pragma unroll
      for (int mt = 0; mt < 4; ++mt)
        #pragma unroll
        for (int nt = 0; nt < 4; ++nt)
          acc[mt][nt] = __builtin_amdgcn_mfma_f32_16x16x32_bf16(a[mt], b[nt], acc[mt][nt], 0, 0, 0);
    }
    __syncthreads();
  }
  const int cn = lane & 15;
  const int cr = (lane >> 4) * 4;
  #pragma unroll
  for (int mt = 0; mt < 4; ++mt) {
    #pragma unroll
    for (int nt = 0; nt < 4; ++nt) {
      const int n = n0 + wc + nt * 16 + cn;
      const float bn = bias[n];
      #pragma unroll
      for (int i = 0; i < 4; ++i) {
        const int m = m0 + wr + mt * 16 + cr + i;
        float x = acc[mt][nt][i] + bn;
        float s = x / (1.0f + __expf(-x));
        out[(size_t)m * N + n] = s * mulp[(size_t)m * N + n];
      }
    }
  }
}

extern "C" void kernel_launch(void* const* d_in, const int* in_sizes, int n_in,
                              void* d_out, int out_size, void* d_ws, size_t ws_size,
                              hipStream_t stream) {
  const float* inp    = (const float*)d_in[0];
  const int*   qw     = (const int*)d_in[1];
  const float* scales = (const float*)d_in[2];
  const int*   qzeros = (const int*)d_in[3];
  const float* bias   = (const float*)d_in[4];
  const float* mulp   = (const float*)d_in[5];
  float*       out    = (float*)d_out;

  const int N = in_sizes[4];
  const int K = (int)(((long long)in_sizes[1] * 8) / N);
  const int M = (int)((long long)in_sizes[0] / K);
  const int G = K / (in_sizes[2] / N);

  const size_t btBytes = (size_t)N * K * sizeof(short);
  const size_t aBytes  = (size_t)M * K * sizeof(short);

  if (ws_size >= btBytes + aBytes) {
    short* Bt  = (short*)d_ws;
    short* Abf = (short*)((char*)d_ws + btBytes);
    const long long nA = (long long)M * K;

    const bool dqOk = (N & 255) == 0 && (K & 63) == 0 && G >= 64 && (G & 63) == 0
                      && (nA & 7) == 0;
    if (dqOk) {
      const int nDq = (K / 64) * (N / 256);
      const int nAc = (int)((nA / 8 + 255) / 256);
      prep_kernel<<<dim3((unsigned)(nDq + nAc)), dim3(256), 0, stream>>>(
          qw, scales, qzeros, Bt, inp, Abf, K, N, G, nDq, nA);
    } else {
      dim3 dq_grid(K / 64, (N / 8) / 16);
      dequant_kernel_v0<<<dq_grid, dim3(256), 0, stream>>>(qw, scales, qzeros, Bt, K, N, G);
      aconv_kernel<<<dim3((unsigned)((nA / 8 + 255) / 256)), dim3(256), 0, stream>>>(inp, Abf, nA);
    }

    if ((M & 255) == 0 && (N & 255) == 0 && (K & 63) == 0) {
      dim3 grid((unsigned)((N >> 8) * (M >> 8)));
      gemm256_silu_mul_kernel<<<grid, dim3(512), 0, stream>>>(Abf, Bt, bias, mulp, out, M, N, K);
    } else {
      dim3 grid(N / 128, M / 128);
      gemm_silu_mul_kernel<<<grid, dim3(256), 0, stream>>>(Abf, Bt, bias, mulp, out, M, N, K);
    }
  } else {
    dim3 grid(N / BN, M / BM);
    woq_silu_mul_kernel<<<grid, dim3(256), 0, stream>>>(inp, qw, scales, qzeros,
                                                        bias, mulp, out, M, N, K, G);
  }
}